// Round 8
// baseline (67.506 us; speedup 1.0000x reference)
//
#include <hip/hip_runtime.h>

#define S 512
#define B 128
#define H 1024

// ---------------------------------------------------------------------------
// calc_u (single kernel): u = hidden @ W, [128,1024]x[1024,1024].
// Grid 256 = 16 bg x 16 ht. Block computes 8 b x 64 h with FULL K via
// 16-way k-split across threads + LDS reduce:
//   thread (th,kg): th=t&15 owns 4 h, kg=t>>4 owns 64 k; 8 b accumulators;
//   2048 FMA/thread (~1.7us across 256 CUs). W loads: 16 lanes x 16B = 256B
//   contiguous per kg-quarter (4 segments/wave-instr). hidden loads: 4-unique
//   broadcast gather per instr, L1-served, hidden under FMA issue.
// LDS: red[16][8][64] floats = 32 KB; 128 threads do the 16-way reduce.
// Replaces the former part+reduce pair (two launches, 8 MB round trip).
// Deterministic: fixed reduction order.
// ---------------------------------------------------------------------------
__global__ __launch_bounds__(256) void calc_u_fused(const float* __restrict__ hidden,
                                                    const float* __restrict__ W,
                                                    float* __restrict__ u) {
    const int t  = threadIdx.x;
    const int th = t & 15;            // h-sub: 4 h each -> 64 h per block
    const int kg = t >> 4;            // 0..15, 64 k each
    const int bg = blockIdx.x & 15;   // 16 groups of 8 b
    const int ht = blockIdx.x >> 4;   // 16 tiles of 64 h
    const int b0 = bg * 8;
    const int h0 = ht * 64 + th * 4;
    const int k0 = kg * 64;

    float4 acc[8];
#pragma unroll
    for (int j = 0; j < 8; ++j) acc[j] = make_float4(0.f, 0.f, 0.f, 0.f);

#pragma unroll 4
    for (int kk = 0; kk < 64; ++kk) {
        const int k = k0 + kk;
        const float4 w = *reinterpret_cast<const float4*>(W + (size_t)k * H + h0);
#pragma unroll
        for (int j = 0; j < 8; ++j) {
            const float hb = hidden[(size_t)(b0 + j) * H + k];  // L1 broadcast
            acc[j].x = fmaf(hb, w.x, acc[j].x);
            acc[j].y = fmaf(hb, w.y, acc[j].y);
            acc[j].z = fmaf(hb, w.z, acc[j].z);
            acc[j].w = fmaf(hb, w.w, acc[j].w);
        }
    }

    __shared__ float red[16][8][64];   // [kg][b][h_local] = 32 KB
#pragma unroll
    for (int j = 0; j < 8; ++j)
        *reinterpret_cast<float4*>(&red[kg][j][th * 4]) = acc[j];
    __syncthreads();

    if (t < 128) {
        const int b  = t >> 4;          // 0..7
        const int hq = (t & 15) * 4;    // 0..60
        float4 s = *reinterpret_cast<const float4*>(&red[0][b][hq]);
#pragma unroll
        for (int g = 1; g < 16; ++g) {
            const float4 v = *reinterpret_cast<const float4*>(&red[g][b][hq]);
            s.x += v.x; s.y += v.y; s.z += v.z; s.w += v.w;
        }
        *reinterpret_cast<float4*>(u + (size_t)(b0 + b) * H + ht * 64 + hq) = s;
    }
}

// ---------------------------------------------------------------------------
// calc_scores: scores[b][s] = dot(enc[s][b][:], u[b][:]).  (R3-proven form)
// Wave w: b = w&127, sg = w>>7; s in [sg*8, sg*8+8). u[b] in 16 VGPRs.
// Plain cacheable float4 loads (nt measured -1.9us; fabric-capped ~5.4 TB/s
// either way). No fences/atomics (R2: fence 13x; R7: scoped-atomic tail
// costs more than the separate softmax kernel). Carries the 268 MB stream.
// ---------------------------------------------------------------------------
__global__ __launch_bounds__(256) void calc_scores(const float* __restrict__ enc,
                                                   const float* __restrict__ u,
                                                   float* __restrict__ scores) {
    const int wid  = threadIdx.x >> 6;
    const int lane = threadIdx.x & 63;
    const int w  = blockIdx.x * 4 + wid;   // 0..8191
    const int b  = w & (B - 1);
    const int sg = w >> 7;                 // 0..63
    const int s0 = sg * 8;

    const float4* __restrict__ u4 = reinterpret_cast<const float4*>(u + (size_t)b * H);
    const float4 uu0 = u4[lane];
    const float4 uu1 = u4[64 + lane];
    const float4 uu2 = u4[128 + lane];
    const float4 uu3 = u4[192 + lane];

    float acc[8];
#pragma unroll
    for (int j = 0; j < 8; ++j) {
        const float4* __restrict__ e4 =
            reinterpret_cast<const float4*>(enc + ((size_t)(s0 + j) * B + b) * H);
        const float4 e0 = e4[lane];
        const float4 e1 = e4[64 + lane];
        const float4 e2 = e4[128 + lane];
        const float4 e3 = e4[192 + lane];
        float a = e0.x * uu0.x + e0.y * uu0.y + e0.z * uu0.z + e0.w * uu0.w;
        a = fmaf(e1.x, uu1.x, a); a = fmaf(e1.y, uu1.y, a);
        a = fmaf(e1.z, uu1.z, a); a = fmaf(e1.w, uu1.w, a);
        a = fmaf(e2.x, uu2.x, a); a = fmaf(e2.y, uu2.y, a);
        a = fmaf(e2.z, uu2.z, a); a = fmaf(e2.w, uu2.w, a);
        a = fmaf(e3.x, uu3.x, a); a = fmaf(e3.y, uu3.y, a);
        a = fmaf(e3.z, uu3.z, a); a = fmaf(e3.w, uu3.w, a);
        acc[j] = a;
    }
#pragma unroll
    for (int j = 0; j < 8; ++j)
#pragma unroll
        for (int off = 32; off >= 1; off >>= 1)
            acc[j] += __shfl_xor(acc[j], off, 64);

    if (lane == 0) {
        float4* sp = reinterpret_cast<float4*>(scores + (size_t)b * S + s0);
        sp[0] = make_float4(acc[0], acc[1], acc[2], acc[3]);
        sp[1] = make_float4(acc[4], acc[5], acc[6], acc[7]);
    }
}

// ---------------------------------------------------------------------------
// softmax over s per b. b_attn never computed: constant per row -> cancels.
// ---------------------------------------------------------------------------
__global__ __launch_bounds__(256) void softmax_rows(const float* __restrict__ scores,
                                                    float* __restrict__ out) {
    const int b = blockIdx.x;
    const int t = threadIdx.x;
    const int wid = t >> 6, lane = t & 63;
    const float* __restrict__ row = scores + (size_t)b * S;
    float v0 = row[t];
    float v1 = row[t + 256];

    __shared__ float sm[4], ss[4];

    float m = fmaxf(v0, v1);
#pragma unroll
    for (int off = 32; off >= 1; off >>= 1)
        m = fmaxf(m, __shfl_xor(m, off, 64));
    if (lane == 0) sm[wid] = m;
    __syncthreads();
    m = fmaxf(fmaxf(sm[0], sm[1]), fmaxf(sm[2], sm[3]));

    float e0 = __expf(v0 - m);
    float e1 = __expf(v1 - m);
    float sum = e0 + e1;
#pragma unroll
    for (int off = 32; off >= 1; off >>= 1)
        sum += __shfl_xor(sum, off, 64);
    if (lane == 0) ss[wid] = sum;
    __syncthreads();
    sum = ss[0] + ss[1] + ss[2] + ss[3];

    const float inv = 1.f / sum;
    out[(size_t)b * S + t]       = e0 * inv;
    out[(size_t)b * S + t + 256] = e1 * inv;
}

extern "C" void kernel_launch(void* const* d_in, const int* in_sizes, int n_in,
                              void* d_out, int out_size, void* d_ws, size_t ws_size,
                              hipStream_t stream) {
    const float* hidden = (const float*)d_in[0];   // [1,B,H]
    const float* enc    = (const float*)d_in[1];   // [S,B,H]
    const float* W      = (const float*)d_in[2];   // [H,H]
    // d_in[3] = b_attn: unused — constant per row, cancels in softmax.

    float* u      = (float*)d_ws;        // B*H floats
    float* scores = u + (size_t)B * H;   // B*S floats
    float* out    = (float*)d_out;       // [B,1,S]

    calc_u_fused<<<256,  256, 0, stream>>>(hidden, W, u);
    calc_scores <<<2048, 256, 0, stream>>>(enc, u, scores);
    softmax_rows<<<128,  256, 0, stream>>>(scores, out);
}

// Round 9
// 57.711 us; speedup vs baseline: 1.1697x; 1.1697x over previous
//
#include <hip/hip_runtime.h>

#define S 512
#define B 128
#define H 1024

// ---------------------------------------------------------------------------
// calc_u_one: u = hidden @ W in ONE kernel. Grid 256 = 16 bg x 16 ht;
// block computes 8 b x 64 h over full K via in-block 16-way k-split.
//   Phase 1: stage hidden[b0:b0+8][0:1024] into LDS hs[8][1028] (pad 4 ->
//            1028%32=4 bank skew per row). Coalesced float4, 8 loads/thread.
//   Phase 2: thread (th=t&15 -> 4 h, kg=t>>4 -> 64 k). Inner loop uses
//            kperm=(kk+kg*8)&63 so the wave's 4 kg-groups read banks
//            {0,8,16,24} (16-lane broadcast each) -> conflict-free LDS
//            reads. R8's mistake (per-lane global gathers for hidden) is
//            gone: hidden now comes from LDS, W stays global float4
//            (4x256B segments/instr). 2048 FMA/thread (~1.7us VALU).
//   Phase 3: 16-way reduce via red[16][8][64] (32 KB), threads t<128,
//            float4 write of u. Deterministic (fixed order per build).
// LDS 65 KB, 1 block/CU; ILP (unroll) hides W L2 latency.
// ---------------------------------------------------------------------------
__global__ __launch_bounds__(256) void calc_u_one(const float* __restrict__ hidden,
                                                  const float* __restrict__ W,
                                                  float* __restrict__ u) {
    const int t  = threadIdx.x;
    const int th = t & 15;            // h-quad: 4 h each -> 64 h per block
    const int kg = t >> 4;            // 0..15, owns 64 k
    const int bg = blockIdx.x & 15;   // 8-b group
    const int ht = blockIdx.x >> 4;   // 64-h stripe
    const int b0 = bg * 8;
    const int h0 = ht * 64 + th * 4;

    __shared__ float hs[8][1028];     // staged hidden rows (+4 pad: bank skew)
    __shared__ float red[16][8][64];  // kg-partials for the reduce

    // Phase 1: stage hidden (coalesced; one row per i, 256 float4/row)
    const float4* __restrict__ hv = reinterpret_cast<const float4*>(hidden + (size_t)b0 * H);
#pragma unroll
    for (int i = 0; i < 8; ++i) {
        const float4 v = hv[i * 256 + t];
        *reinterpret_cast<float4*>(&hs[i][t * 4]) = v;
    }
    __syncthreads();

    // Phase 2: k-slice accumulation
    float4 acc[8];
#pragma unroll
    for (int j = 0; j < 8; ++j) acc[j] = make_float4(0.f, 0.f, 0.f, 0.f);

#pragma unroll 4
    for (int kk = 0; kk < 64; ++kk) {
        const int k = kg * 64 + ((kk + kg * 8) & 63);   // bank-skewed walk
        const float4 w = *reinterpret_cast<const float4*>(W + (size_t)k * H + h0);
#pragma unroll
        for (int j = 0; j < 8; ++j) {
            const float hb = hs[j][k];                  // LDS broadcast, conflict-free
            acc[j].x = fmaf(hb, w.x, acc[j].x);
            acc[j].y = fmaf(hb, w.y, acc[j].y);
            acc[j].z = fmaf(hb, w.z, acc[j].z);
            acc[j].w = fmaf(hb, w.w, acc[j].w);
        }
    }

    __syncthreads();   // hs no longer needed; reuse-free handoff to red
#pragma unroll
    for (int j = 0; j < 8; ++j)
        *reinterpret_cast<float4*>(&red[kg][j][th * 4]) = acc[j];
    __syncthreads();

    // Phase 3: 16-way reduce, 128 threads
    if (t < 128) {
        const int b  = t >> 4;          // 0..7
        const int hq = (t & 15) * 4;    // 0..60
        float4 s = *reinterpret_cast<const float4*>(&red[0][b][hq]);
#pragma unroll
        for (int g = 1; g < 16; ++g) {
            const float4 v = *reinterpret_cast<const float4*>(&red[g][b][hq]);
            s.x += v.x; s.y += v.y; s.z += v.z; s.w += v.w;
        }
        *reinterpret_cast<float4*>(u + (size_t)(b0 + b) * H + ht * 64 + hq) = s;
    }
}

// ---------------------------------------------------------------------------
// calc_scores: scores[b][s] = dot(enc[s][b][:], u[b][:]).  (R3-proven form)
// Wave w: b = w&127, sg = w>>7; s in [sg*8, sg*8+8). u[b] in 16 VGPRs.
// Plain cacheable float4 loads (nt measured +1.9us; ~5.3-5.4 TB/s effective
// either way). No fences/atomics (R2: fence 13x; R7: scoped-atomic tail
// costs more than the separate softmax kernel). Carries the 268 MB stream.
// ---------------------------------------------------------------------------
__global__ __launch_bounds__(256) void calc_scores(const float* __restrict__ enc,
                                                   const float* __restrict__ u,
                                                   float* __restrict__ scores) {
    const int wid  = threadIdx.x >> 6;
    const int lane = threadIdx.x & 63;
    const int w  = blockIdx.x * 4 + wid;   // 0..8191
    const int b  = w & (B - 1);
    const int sg = w >> 7;                 // 0..63
    const int s0 = sg * 8;

    const float4* __restrict__ u4 = reinterpret_cast<const float4*>(u + (size_t)b * H);
    const float4 uu0 = u4[lane];
    const float4 uu1 = u4[64 + lane];
    const float4 uu2 = u4[128 + lane];
    const float4 uu3 = u4[192 + lane];

    float acc[8];
#pragma unroll
    for (int j = 0; j < 8; ++j) {
        const float4* __restrict__ e4 =
            reinterpret_cast<const float4*>(enc + ((size_t)(s0 + j) * B + b) * H);
        const float4 e0 = e4[lane];
        const float4 e1 = e4[64 + lane];
        const float4 e2 = e4[128 + lane];
        const float4 e3 = e4[192 + lane];
        float a = e0.x * uu0.x + e0.y * uu0.y + e0.z * uu0.z + e0.w * uu0.w;
        a = fmaf(e1.x, uu1.x, a); a = fmaf(e1.y, uu1.y, a);
        a = fmaf(e1.z, uu1.z, a); a = fmaf(e1.w, uu1.w, a);
        a = fmaf(e2.x, uu2.x, a); a = fmaf(e2.y, uu2.y, a);
        a = fmaf(e2.z, uu2.z, a); a = fmaf(e2.w, uu2.w, a);
        a = fmaf(e3.x, uu3.x, a); a = fmaf(e3.y, uu3.y, a);
        a = fmaf(e3.z, uu3.z, a); a = fmaf(e3.w, uu3.w, a);
        acc[j] = a;
    }
#pragma unroll
    for (int j = 0; j < 8; ++j)
#pragma unroll
        for (int off = 32; off >= 1; off >>= 1)
            acc[j] += __shfl_xor(acc[j], off, 64);

    if (lane == 0) {
        float4* sp = reinterpret_cast<float4*>(scores + (size_t)b * S + s0);
        sp[0] = make_float4(acc[0], acc[1], acc[2], acc[3]);
        sp[1] = make_float4(acc[4], acc[5], acc[6], acc[7]);
    }
}

// ---------------------------------------------------------------------------
// softmax over s per b. b_attn never computed: constant per row -> cancels.
// ---------------------------------------------------------------------------
__global__ __launch_bounds__(256) void softmax_rows(const float* __restrict__ scores,
                                                    float* __restrict__ out) {
    const int b = blockIdx.x;
    const int t = threadIdx.x;
    const int wid = t >> 6, lane = t & 63;
    const float* __restrict__ row = scores + (size_t)b * S;
    float v0 = row[t];
    float v1 = row[t + 256];

    __shared__ float sm[4], ss[4];

    float m = fmaxf(v0, v1);
#pragma unroll
    for (int off = 32; off >= 1; off >>= 1)
        m = fmaxf(m, __shfl_xor(m, off, 64));
    if (lane == 0) sm[wid] = m;
    __syncthreads();
    m = fmaxf(fmaxf(sm[0], sm[1]), fmaxf(sm[2], sm[3]));

    float e0 = __expf(v0 - m);
    float e1 = __expf(v1 - m);
    float sum = e0 + e1;
#pragma unroll
    for (int off = 32; off >= 1; off >>= 1)
        sum += __shfl_xor(sum, off, 64);
    if (lane == 0) ss[wid] = sum;
    __syncthreads();
    sum = ss[0] + ss[1] + ss[2] + ss[3];

    const float inv = 1.f / sum;
    out[(size_t)b * S + t]       = e0 * inv;
    out[(size_t)b * S + t + 256] = e1 * inv;
}

extern "C" void kernel_launch(void* const* d_in, const int* in_sizes, int n_in,
                              void* d_out, int out_size, void* d_ws, size_t ws_size,
                              hipStream_t stream) {
    const float* hidden = (const float*)d_in[0];   // [1,B,H]
    const float* enc    = (const float*)d_in[1];   // [S,B,H]
    const float* W      = (const float*)d_in[2];   // [H,H]
    // d_in[3] = b_attn: unused — constant per row, cancels in softmax.

    float* u      = (float*)d_ws;        // B*H floats
    float* scores = u + (size_t)B * H;   // B*S floats
    float* out    = (float*)d_out;       // [B,1,S]

    calc_u_one  <<<256,  256, 0, stream>>>(hidden, W, u);
    calc_scores <<<2048, 256, 0, stream>>>(enc, u, scores);
    softmax_rows<<<128,  256, 0, stream>>>(scores, out);
}